// Round 1
// 2500.655 us; speedup vs baseline: 1.0827x; 1.0827x over previous
//
#include <hip/hip_runtime.h>
#include <stdint.h>

// Problem dims
#define Tn 512
#define Bn 128
#define NTOK (Bn*Tn)     // 65536
#define En 300
#define Hn 300
#define On 9
#define LDK 328          // LDS row stride in shorts (656 B rows, 16B-aligned)
#define HS 60            // hidden units per slice
#define NSL 5            // slices per direction (5*60 = 300)
#define NCH 8            // batch chunks
#define MC 16            // batch rows per chunk (one m-tile)
#define NG 240           // 4*HS gate columns per block
#define GLD 244          // padded Gsm row stride (floats): 4*240%32==0 was a 4-way write conflict
#define NBLK (2*NCH*NSL) // 80 blocks
#define NTHR 960         // 15 waves = 1 m-tile x 15 n-tiles; == MC*HS cell threads

#define HXW 304          // g_hx row stride in dwords (one tagged packet per hidden unit)
#define HXSLOT (Bn*HXW)  // dwords per parity slot
#define HXDIR (2*HXSLOT) // dwords per direction (2 parity slots)

typedef short s4v __attribute__((ext_vector_type(4)));
typedef short s8v __attribute__((ext_vector_type(8)));
typedef float f4v __attribute__((ext_vector_type(4)));

// ---- static device scratch (d_ws unused) ----
__device__ unsigned short g_hcat[NTOK * 2 * Hn];   // 78,643,200 B — h outputs
// Tagged h-exchange packets: dword = (bf16(h) << 16) | produced_step.
// The data IS the flag: a single atomic dword store publishes value+validity,
// so producers need no fence and consumers poll the data directly.
__device__ unsigned int   g_hx[2 * HXDIR];         // 1,245,184 B

__device__ inline float b2f(unsigned short u){ unsigned v = ((unsigned)u) << 16; float f; __builtin_memcpy(&f, &v, 4); return f; }
__device__ inline unsigned short f2b(float f){ unsigned u; __builtin_memcpy(&u, &f, 4); u = u + 0x7fffu + ((u >> 16) & 1u); return (unsigned short)(u >> 16); }
__device__ inline float sigf(float x){ return 1.f / (1.f + __expf(-x)); }
__device__ inline float tanh_f(float x){ return 2.f / (1.f + __expf(-2.f * x)) - 1.f; }

// LDS-only barrier: drains lgkmcnt but NOT vmcnt, so in-flight global stores
// (the fire-and-forget h/hcat publishes) never sit on the critical path.
__device__ inline void bar_lgkm(){ asm volatile("s_waitcnt lgkmcnt(0)\n\ts_barrier" ::: "memory"); }

// ---------------- K0: init h-exchange tags to 0xFFFF (never matches a real step) ----------------
__global__ __launch_bounds__(256) void k_zero()
{
    const int i = blockIdx.x * 256 + threadIdx.x;
    const int stride = gridDim.x * 256;
    for (int j = i; j < 2 * HXDIR; j += stride) g_hx[j] = 0xFFFFu;
}

// ---------------- K1: fused bidirectional LSTM recurrence ----------------
// Tagged-packet exchange (this round's change): per step the serial chain is now
//   cell -> h-packet store (no fence) -> [propagation] -> peer poll returns tag+data
// removing the producer vmcnt drain and the separate flag publish/detect hops.
__global__ __launch_bounds__(NTHR, 4) void k_lstm(
    const int* __restrict__ x, const float* __restrict__ emb,
    const float* __restrict__ W_ih_f, const float* __restrict__ W_hh_f, const float* __restrict__ b_f,
    const float* __restrict__ W_ih_b, const float* __restrict__ W_hh_b, const float* __restrict__ b_b)
{
    const int bi    = blockIdx.x;
    const int dir   = bi / (NCH * NSL);
    const int rem   = bi % (NCH * NSL);
    const int chunk = rem / NSL;
    const int slice = rem % NSL;
    const int j0    = slice * HS;
    const int b0    = chunk * MC;

    const float* Wih  = dir ? W_ih_b : W_ih_f;
    const float* Whh  = dir ? W_hh_b : W_hh_f;
    const float* bias = dir ? b_b    : b_f;
    unsigned int* hxd = g_hx + dir * HXDIR;

    __shared__ __align__(16) unsigned short Aemb[2][MC * LDK]; // 21 KB emb staging, double-buffered
    __shared__ __align__(16) unsigned short Hb[MC * LDK];      // 10.5 KB h staging
    __shared__ __align__(16) float Gsm[MC * GLD];              // 15.6 KB gate dump (padded stride)

    const int tid  = threadIdx.x;
    const int lane = tid & 63;
    const int wid  = tid >> 6;              // 15 waves
    const int n0   = wid * 16;              // 15 n-tiles (240 gate cols); single m-tile
    const int kq   = (lane >> 4) * 8;       // k-subgroup within 32

    // ---- preload weight B-fragments (fp32 -> bf16 once, weight-stationary) ----
    // local gate col layout: [i(60) | f(60) | g(60) | o(60)]
    const int nloc = n0 + (lane & 15);      // 0..239
    const int q    = nloc / HS;             // gate index 0..3
    const int jjn  = nloc % HS;
    const int grow = q * Hn + j0 + jjn;     // global row in [1200]
    s8v bih[10], bhh[10];
#pragma unroll
    for (int kc = 0; kc < 10; kc++) {
        int kb = kc * 32 + kq;
        s8v fi = {0,0,0,0,0,0,0,0}, fh = {0,0,0,0,0,0,0,0};
#pragma unroll
        for (int j = 0; j < 8; j++) {
            int k = kb + j;
            if (k < En) {
                fi[j] = (short)f2b(Wih[grow * En + k]);
                fh[j] = (short)f2b(Whh[grow * Hn + k]);
            }
        }
        bih[kc] = fi; bhh[kc] = fh;
    }

    // ---- per-thread cell state: tid <-> (batch row ebl, unit ejj); NTHR == MC*HS ----
    const int ebl = tid / HS;   // 0..15
    const int ejj = tid % HS;   // 0..59
    const float bi_i = bias[0 * Hn + j0 + ejj];
    const float bi_f = bias[1 * Hn + j0 + ejj];
    const float bi_g = bias[2 * Hn + j0 + ejj];
    const float bi_o = bias[3 * Hn + j0 + ejj];
    float creg = 0.f;
    const bool pub = ((ejj & 1) == 0);      // even-ejj lanes store packed hcat dwords
    // pairs are (even ejj, ejj+1); the last lane of every wave has odd ejj -> no
    // pair crosses a wave boundary.

    // ---- P3 assignment: 5 packets per thread (MC*300 == 5*NTHR exactly) ----
    int goffA[5], loffA[5];
#pragma unroll
    for (int j = 0; j < 5; j++) {
        int i = tid + j * NTHR;             // 0..4799
        int r = i / Hn, c = i - r * Hn;     // row 0..15, unit 0..299
        goffA[j] = (b0 + r) * HXW + c;
        loffA[j] = r * LDK + c;
    }

    // ---- prologue: stage emb for s=0 into Aemb[0]; zero Hb pad cols [300,320) ----
    {
        const int t0 = dir ? (Tn - 1) : 0;
        for (int i = tid; i < MC * 80; i += NTHR) {
            int r = i / 80, c = i - r * 80;
            s4v v = {0, 0, 0, 0};
            if (c < 75) {
                int xi = x[(b0 + r) * Tn + t0];
                float4 f = *(const float4*)(emb + (size_t)xi * En + c * 4);
                v[0] = (short)f2b(f.x); v[1] = (short)f2b(f.y);
                v[2] = (short)f2b(f.z); v[3] = (short)f2b(f.w);
            }
            *(s4v*)&Aemb[0][r * LDK + c * 4] = v;
        }
        // MFMA2 reads shorts [0,320) per row; P3 only fills [0,300). Zero the pad
        // once (garbage here could be NaN; NaN*0 = NaN would poison the MFMA).
        if (tid < MC * 20) {
            int r = tid / 20, c = 300 + (tid % 20);
            Hb[r * LDK + c] = 0;
        }
        __syncthreads();
    }

#pragma unroll 1
    for (int s = 0; s < Tn; s++) {
        const int t   = dir ? (Tn - 1 - s) : s;
        const int cur = s & 1, nxt = cur ^ 1;

        // issue emb prefetch for step s+1 into registers FIRST (max overlap)
        float4 pf[2];
        const bool do_pf = (s + 1 < Tn);
        if (do_pf) {
            const int tn1 = dir ? (Tn - 2 - s) : (s + 1);
#pragma unroll
            for (int k = 0; k < 2; k++) {
                int i = tid + k * NTHR;            // < 1920; valid when < 1280 = MC*80
                if (i < MC * 80) {
                    int r = i / 80, c = i - r * 80;
                    if (c < 75) {
                        int xi = x[(b0 + r) * Tn + tn1];
                        pf[k] = *(const float4*)(emb + (size_t)xi * En + c * 4);
                    }
                }
            }
        }

        // MFMA1: input projection part from Aemb[cur] (runs during the wait window)
        f4v acc = {0.f, 0.f, 0.f, 0.f};
        {
            const unsigned short* abase = &Aemb[cur][(lane & 15) * LDK + kq];
#pragma unroll
            for (int kc = 0; kc < 10; kc++) {
                s8v a = *(const s8v*)(abase + kc * 32);
                acc = __builtin_amdgcn_mfma_f32_16x16x32_bf16(a, bih[kc], acc, 0, 0, 0);
            }
        }

        if (s) {
            // P3: poll tagged packets directly — detect and load are ONE hop.
            // All 5 loads issued concurrently; only pending ones are re-issued.
            const unsigned tgt = (unsigned)(s - 1);
            const unsigned int* hsrc = hxd + (s & 1) * HXSLOT;
            unsigned int pv[5];
            unsigned pend = 0x1fu;
            do {
#pragma unroll
                for (int j = 0; j < 5; j++)
                    if (pend & (1u << j))
                        pv[j] = __hip_atomic_load(hsrc + goffA[j],
                                                  __ATOMIC_RELAXED, __HIP_MEMORY_SCOPE_AGENT);
#pragma unroll
                for (int j = 0; j < 5; j++)
                    if ((pv[j] & 0xffffu) == tgt) pend &= ~(1u << j);
            } while (pend);
#pragma unroll
            for (int j = 0; j < 5; j++)
                Hb[loffA[j]] = (unsigned short)(pv[j] >> 16);

            bar_lgkm();   // bar B: Hb ready (LDS only — no vmcnt drain)

            // MFMA2: recurrent part from Hb
            {
                const unsigned short* abase = &Hb[(lane & 15) * LDK + kq];
#pragma unroll
                for (int kc = 0; kc < 10; kc++) {
                    s8v a = *(const s8v*)(abase + kc * 32);
                    acc = __builtin_amdgcn_mfma_f32_16x16x32_bf16(a, bhh[kc], acc, 0, 0, 0);
                }
            }
        }
        // s == 0: h_0 == 0, recurrent term is zero — skip P3/MFMA2 entirely.

        // dump gates (C layout: col=lane&15, row=(lane>>4)*4+reg; single m-tile)
        {
            int col   = n0 + (lane & 15);
            int rbase = (lane >> 4) * 4;
#pragma unroll
            for (int r2 = 0; r2 < 4; r2++) Gsm[(rbase + r2) * GLD + col] = acc[r2];
        }
        bar_lgkm();   // bar C: Gsm ready

        // elementwise LSTM cell + tagged publish (fire-and-forget; no fence needed
        // because tag and data share one atomic dword)
        {
            float gi  = Gsm[ebl * GLD + 0 * HS + ejj] + bi_i;
            float gf  = Gsm[ebl * GLD + 1 * HS + ejj] + bi_f;
            float gg2 = Gsm[ebl * GLD + 2 * HS + ejj] + bi_g;
            float go  = Gsm[ebl * GLD + 3 * HS + ejj] + bi_o;
            float iv = sigf(gi), fv = sigf(gf), gv = tanh_f(gg2), ov = sigf(go);
            creg = fv * creg + iv * gv;
            float h = ov * tanh_f(creg);
            unsigned hb16 = (unsigned)f2b(h);

            __hip_atomic_store(hxd + ((s + 1) & 1) * HXSLOT + (b0 + ebl) * HXW + (j0 + ejj),
                               (hb16 << 16) | (unsigned)s,
                               __ATOMIC_RELAXED, __HIP_MEMORY_SCOPE_AGENT);

            float hn = __shfl_down(h, 1);          // partner (ejj+1) in same wave
            if (pub) {
                unsigned pkt = hb16 | ((unsigned)f2b(hn) << 16);
                __hip_atomic_store((unsigned int*)g_hcat
                                       + (((size_t)((b0 + ebl) * Tn + t)) * (2 * Hn) + dir * Hn + j0 + ejj) / 2,
                                   pkt, __ATOMIC_RELAXED, __HIP_MEMORY_SCOPE_AGENT);
            }
        }

        // writeback prefetched emb(s+1) -> Aemb[nxt] (covered by bar D)
        if (do_pf) {
#pragma unroll
            for (int k = 0; k < 2; k++) {
                int i = tid + k * NTHR;
                if (i < MC * 80) {
                    int r = i / 80, c = i - r * 80;
                    s4v v = {0, 0, 0, 0};
                    if (c < 75) {
                        v[0] = (short)f2b(pf[k].x); v[1] = (short)f2b(pf[k].y);
                        v[2] = (short)f2b(pf[k].z); v[3] = (short)f2b(pf[k].w);
                    }
                    *(s4v*)&Aemb[nxt][r * LDK + c * 4] = v;
                }
            }
        }
        bar_lgkm();   // bar D: Aemb[nxt] visible (LDS only — h stores drain in background)
    }
}

// ---------------- K2: fused out-projection + softmax, one wave per 16 positions ----------------
__global__ __launch_bounds__(256) void k_out(
    const float* __restrict__ W_lin, const float* __restrict__ b_lin, float* __restrict__ out)
{
    __shared__ float Wl[On * 2 * Hn];  // 21.6 KB
    __shared__ float bl[On];
    const int tid = threadIdx.x;
    for (int i = tid; i < On * 2 * Hn; i += 256) Wl[i] = W_lin[i];
    if (tid < On) bl[tid] = b_lin[tid];
    __syncthreads();

    const int lane = tid & 63;
    const int w    = tid >> 6;
    const int wg   = blockIdx.x * 4 + w;      // 4096 waves
    for (int it = 0; it < 16; it++) {
        const int p = wg * 16 + it;           // 0..65535
        const unsigned short* row = g_hcat + (size_t)p * (2 * Hn);
        float part[On];
#pragma unroll
        for (int o = 0; o < On; o++) part[o] = 0.f;
        for (int c = 0; c < 10; c++) {
            int k = lane + 64 * c;
            if (k < 2 * Hn) {
                float v = b2f(row[k]);
#pragma unroll
                for (int o = 0; o < On; o++) part[o] += v * Wl[o * (2 * Hn) + k];
            }
        }
#pragma unroll
        for (int off = 32; off >= 1; off >>= 1) {
#pragma unroll
            for (int o = 0; o < On; o++) part[o] += __shfl_xor(part[o], off, 64);
        }
        if (lane == 0) {
            float lg[On];
            float m = -1e30f;
#pragma unroll
            for (int o = 0; o < On; o++) { lg[o] = part[o] + bl[o]; m = fmaxf(m, lg[o]); }
            float ssum = 0.f;
#pragma unroll
            for (int o = 0; o < On; o++) { lg[o] = __expf(lg[o] - m); ssum += lg[o]; }
            float inv = 1.f / ssum;
#pragma unroll
            for (int o = 0; o < On; o++) out[(size_t)p * On + o] = lg[o] * inv;
        }
    }
}

// ---------------- host launcher ----------------
extern "C" void kernel_launch(void* const* d_in, const int* in_sizes, int n_in,
                              void* d_out, int out_size, void* d_ws, size_t ws_size,
                              hipStream_t stream)
{
    (void)in_sizes; (void)n_in; (void)out_size; (void)d_ws; (void)ws_size;
    const int* x = (const int*)d_in[0];
    const float* emb   = (const float*)d_in[1];
    const float* Wih_f = (const float*)d_in[2];
    const float* Whh_f = (const float*)d_in[3];
    const float* bf    = (const float*)d_in[4];
    const float* Wih_b = (const float*)d_in[5];
    const float* Whh_b = (const float*)d_in[6];
    const float* bb    = (const float*)d_in[7];
    const float* Wlin  = (const float*)d_in[8];
    const float* blin  = (const float*)d_in[9];
    float* out = (float*)d_out;

    k_zero<<<128, 256, 0, stream>>>();

    void* args[] = {
        (void*)&x, (void*)&emb,
        (void*)&Wih_f, (void*)&Whh_f, (void*)&bf,
        (void*)&Wih_b, (void*)&Whh_b, (void*)&bb
    };
    hipLaunchCooperativeKernel((const void*)k_lstm, dim3(NBLK), dim3(NTHR), args, 0, stream);

    k_out<<<1024, 256, 0, stream>>>(Wlin, blin, out);
}

// Round 4
// 2031.679 us; speedup vs baseline: 1.3327x; 1.2308x over previous
//
#include <hip/hip_runtime.h>
#include <stdint.h>

// Problem dims
#define Tn 512
#define Bn 128
#define NTOK (Bn*Tn)     // 65536
#define En 300
#define Hn 300
#define On 9
#define LDK 328          // LDS row stride in shorts (656 B rows, 16B-aligned)
#define HS 60            // hidden units per slice
#define NSL 5            // slices per direction (5*60 = 300)
#define NCH 8            // batch chunks
#define MC 16            // batch rows per chunk (one m-tile)
#define GLD 244          // padded Gsm row stride (floats): 4*240%32==0 was a 4-way write conflict
#define NBLK (2*NCH*NSL) // 80 blocks
#define NTHR 960         // 15 waves = 1 m-tile x 15 n-tiles; == MC*HS cell threads

#define HXW 304          // g_hx row stride in dwords (one tagged packet per hidden unit)
#define HXSLOT (Bn*HXW)  // dwords per parity slot
#define HXDIR (2*HXSLOT) // dwords per direction (2 parity slots)

typedef short s4v __attribute__((ext_vector_type(4)));
typedef short s8v __attribute__((ext_vector_type(8)));
typedef float f4v __attribute__((ext_vector_type(4)));

// ---- static device scratch (d_ws unused) ----
__device__ unsigned short g_hcat[NTOK * 2 * Hn];   // 78,643,200 B — h outputs
// Tagged h-exchange packets: dword = (bf16(h) << 16) | produced_step.
// The data IS the flag: one atomic dword store publishes value+validity.
__device__ unsigned int   g_hx[2 * HXDIR];         // 622,592 B

__device__ inline float b2f(unsigned short u){ unsigned v = ((unsigned)u) << 16; float f; __builtin_memcpy(&f, &v, 4); return f; }
__device__ inline unsigned short f2b(float f){ unsigned u; __builtin_memcpy(&u, &f, 4); u = u + 0x7fffu + ((u >> 16) & 1u); return (unsigned short)(u >> 16); }
__device__ inline float sigf(float x){ return 1.f / (1.f + __expf(-x)); }
__device__ inline float tanh_f(float x){ return 2.f / (1.f + __expf(-2.f * x)) - 1.f; }

// LDS-only barrier: drains lgkmcnt but NOT vmcnt, so in-flight global stores
// (the fire-and-forget h/hcat publishes) never sit on the critical path.
__device__ inline void bar_lgkm(){ asm volatile("s_waitcnt lgkmcnt(0)\n\ts_barrier" ::: "memory"); }

// ---------------- K0: init h-exchange tags to 0xFFFF (never matches a real step) ----------------
__global__ __launch_bounds__(256) void k_zero()
{
    const int i = blockIdx.x * 256 + threadIdx.x;
    const int stride = gridDim.x * 256;
    for (int j = i; j < 2 * HXDIR; j += stride) g_hx[j] = 0xFFFFu;
}

// ---------------- K1: fused bidirectional LSTM recurrence ----------------
// R4 changes vs the proven R1 kernel (agent-scope protocol unchanged):
//  (1) emb prefetch issued AFTER the poll (x indices served from LDS) — the
//      poll's in-order vmcnt wait no longer drains the ~1800cy x->emb chain.
//  (2) poll = 4 UNCONDITIONAL atomic loads (straight-line, compiler-batchable
//      behind one waitcnt) instead of 5 divergent pend-masked loads.
//  (3) own-slice h is passed through LDS (self-write into Hb after bar C);
//      only the other 4 slices are polled from g_hx.
__global__ __launch_bounds__(NTHR, 4) void k_lstm(
    const int* __restrict__ x, const float* __restrict__ emb,
    const float* __restrict__ W_ih_f, const float* __restrict__ W_hh_f, const float* __restrict__ b_f,
    const float* __restrict__ W_ih_b, const float* __restrict__ W_hh_b, const float* __restrict__ b_b)
{
    const int bi    = blockIdx.x;
    const int dir   = bi / (NCH * NSL);
    const int rem   = bi % (NCH * NSL);
    const int chunk = rem / NSL;
    const int slice = rem % NSL;
    const int j0    = slice * HS;
    const int b0    = chunk * MC;

    const float* Wih  = dir ? W_ih_b : W_ih_f;
    const float* Whh  = dir ? W_hh_b : W_hh_f;
    const float* bias = dir ? b_b    : b_f;
    unsigned int* hxd = g_hx + dir * HXDIR;

    __shared__ __align__(16) unsigned short Aemb[2][MC * LDK]; // 21 KB emb staging, double-buffered
    __shared__ __align__(16) unsigned short Hb[MC * LDK];      // 10.5 KB h staging
    __shared__ __align__(16) float Gsm[MC * GLD];              // 15.6 KB gate dump (padded stride)
    __shared__ int Xl[MC * Tn];                                // 32 KB token ids (kills x-load from pf chain)

    const int tid  = threadIdx.x;
    const int lane = tid & 63;
    const int wid  = tid >> 6;              // 15 waves
    const int n0   = wid * 16;              // 15 n-tiles (240 gate cols); single m-tile
    const int kq   = (lane >> 4) * 8;       // k-subgroup within 32

    // ---- preload weight B-fragments (fp32 -> bf16 once, weight-stationary) ----
    // local gate col layout: [i(60) | f(60) | g(60) | o(60)]
    const int nloc = n0 + (lane & 15);      // 0..239
    const int q    = nloc / HS;             // gate index 0..3
    const int jjn  = nloc % HS;
    const int grow = q * Hn + j0 + jjn;     // global row in [1200]
    s8v bih[10], bhh[10];
#pragma unroll
    for (int kc = 0; kc < 10; kc++) {
        int kb = kc * 32 + kq;
        s8v fi = {0,0,0,0,0,0,0,0}, fh = {0,0,0,0,0,0,0,0};
#pragma unroll
        for (int j = 0; j < 8; j++) {
            int k = kb + j;
            if (k < En) {
                fi[j] = (short)f2b(Wih[grow * En + k]);
                fh[j] = (short)f2b(Whh[grow * Hn + k]);
            }
        }
        bih[kc] = fi; bhh[kc] = fh;
    }

    // ---- per-thread cell state: tid <-> (batch row ebl, unit ejj); NTHR == MC*HS ----
    const int ebl = tid / HS;   // 0..15
    const int ejj = tid % HS;   // 0..59
    const float bi_i = bias[0 * Hn + j0 + ejj];
    const float bi_f = bias[1 * Hn + j0 + ejj];
    const float bi_g = bias[2 * Hn + j0 + ejj];
    const float bi_o = bias[3 * Hn + j0 + ejj];
    float creg = 0.f;
    const bool pub = ((ejj & 1) == 0);      // even-ejj lanes store packed hcat dwords

    // ---- P3 assignment: 4 packets per thread over the OTHER 4 slices ----
    // (MC * 4*HS == 4*NTHR exactly; own slice [j0,j0+60) comes via LDS self-write)
    int goffA[4], loffA[4];
#pragma unroll
    for (int j = 0; j < 4; j++) {
        int i  = tid + j * NTHR;            // 0..3839
        int r  = i / (4 * HS);              // row 0..15
        int c2 = i - r * (4 * HS);          // 0..239
        int c  = (c2 < j0) ? c2 : (c2 + HS);// skip own slice's 60 columns
        goffA[j] = (b0 + r) * HXW + c;
        loffA[j] = r * LDK + c;
    }

    // ---- prologue: stage emb(s=0) into Aemb[0]; stage token ids; zero Hb pad ----
    {
        const int t0 = dir ? (Tn - 1) : 0;
        for (int i = tid; i < MC * 80; i += NTHR) {
            int r = i / 80, c = i - r * 80;
            s4v v = {0, 0, 0, 0};
            if (c < 75) {
                int xi = x[(b0 + r) * Tn + t0];
                float4 f = *(const float4*)(emb + (size_t)xi * En + c * 4);
                v[0] = (short)f2b(f.x); v[1] = (short)f2b(f.y);
                v[2] = (short)f2b(f.z); v[3] = (short)f2b(f.w);
            }
            *(s4v*)&Aemb[0][r * LDK + c * 4] = v;
        }
        for (int i = tid; i < MC * Tn; i += NTHR) {
            int r = i >> 9, tt = i & (Tn - 1);
            Xl[i] = x[(b0 + r) * Tn + tt];          // Xl[r*512 + t]
        }
        // MFMA2 reads shorts [0,320) per row; only [0,300) is ever filled. Zero
        // the pad once (garbage could be NaN; NaN*0 = NaN poisons the MFMA).
        if (tid < MC * 20) {
            int r = tid / 20, c = 300 + (tid % 20);
            Hb[r * LDK + c] = 0;
        }
        __syncthreads();
    }

#pragma unroll 1
    for (int s = 0; s < Tn; s++) {
        const int t   = dir ? (Tn - 1 - s) : s;
        const int cur = s & 1, nxt = cur ^ 1;

        // MFMA1: input projection part from Aemb[cur] (runs during the wait window)
        f4v acc = {0.f, 0.f, 0.f, 0.f};
        {
            const unsigned short* abase = &Aemb[cur][(lane & 15) * LDK + kq];
#pragma unroll
            for (int kc = 0; kc < 10; kc++) {
                s8v a = *(const s8v*)(abase + kc * 32);
                acc = __builtin_amdgcn_mfma_f32_16x16x32_bf16(a, bih[kc], acc, 0, 0, 0);
            }
        }

        if (s) {
            // P3: poll tagged packets of the other 4 slices. Unconditional
            // straight-line loads -> compiler batches all 4 issues behind one
            // waitcnt; a retry round costs ~1 MALL latency, not 4.
            // Reload-all retry is safe: a satisfied packet cannot change until
            // WE publish step s (peers are blocked in their own step-s+1 poll).
            const unsigned tgt = (unsigned)(s - 1);
            const unsigned int* hsrc = hxd + (s & 1) * HXSLOT;
            unsigned int pv0, pv1, pv2, pv3;
            for (;;) {
                pv0 = __hip_atomic_load(hsrc + goffA[0], __ATOMIC_RELAXED, __HIP_MEMORY_SCOPE_AGENT);
                pv1 = __hip_atomic_load(hsrc + goffA[1], __ATOMIC_RELAXED, __HIP_MEMORY_SCOPE_AGENT);
                pv2 = __hip_atomic_load(hsrc + goffA[2], __ATOMIC_RELAXED, __HIP_MEMORY_SCOPE_AGENT);
                pv3 = __hip_atomic_load(hsrc + goffA[3], __ATOMIC_RELAXED, __HIP_MEMORY_SCOPE_AGENT);
                unsigned bad = ((pv0 ^ tgt) | (pv1 ^ tgt) | (pv2 ^ tgt) | (pv3 ^ tgt)) & 0xffffu;
                if (!bad) break;
            }
            Hb[loffA[0]] = (unsigned short)(pv0 >> 16);
            Hb[loffA[1]] = (unsigned short)(pv1 >> 16);
            Hb[loffA[2]] = (unsigned short)(pv2 >> 16);
            Hb[loffA[3]] = (unsigned short)(pv3 >> 16);
        }

        // emb prefetch for s+1, issued AFTER the poll: its ~900cy HBM latency
        // (token id now comes from LDS, not a dependent global load) hides
        // under MFMA2 + gate dump + cell before the writeback consumes it —
        // and it never sits ahead of poll loads in the in-order vmcnt queue.
        float4 pf[2];
        const bool do_pf = (s + 1 < Tn);
        if (do_pf) {
            const int tn1 = dir ? (Tn - 2 - s) : (s + 1);
#pragma unroll
            for (int k = 0; k < 2; k++) {
                int i = tid + k * NTHR;            // < 1920; valid when < 1280 = MC*80
                if (i < MC * 80) {
                    int r = i / 80, c = i - r * 80;
                    if (c < 75) {
                        int xi = Xl[(r << 9) + tn1];
                        pf[k] = *(const float4*)(emb + (size_t)xi * En + c * 4);
                    }
                }
            }
        }

        if (s) {
            bar_lgkm();   // bar B: Hb ready (LDS only — no vmcnt drain)

            // MFMA2: recurrent part from Hb
            const unsigned short* abase = &Hb[(lane & 15) * LDK + kq];
#pragma unroll
            for (int kc = 0; kc < 10; kc++) {
                s8v a = *(const s8v*)(abase + kc * 32);
                acc = __builtin_amdgcn_mfma_f32_16x16x32_bf16(a, bhh[kc], acc, 0, 0, 0);
            }
        }
        // s == 0: h_0 == 0, recurrent term is zero — skip P3/MFMA2 entirely.

        // dump gates (C layout: col=lane&15, row=(lane>>4)*4+reg; single m-tile)
        {
            int col   = n0 + (lane & 15);
            int rbase = (lane >> 4) * 4;
#pragma unroll
            for (int r2 = 0; r2 < 4; r2++) Gsm[(rbase + r2) * GLD + col] = acc[r2];
        }
        bar_lgkm();   // bar C: Gsm ready

        // elementwise LSTM cell + publishes
        {
            float gi  = Gsm[ebl * GLD + 0 * HS + ejj] + bi_i;
            float gf  = Gsm[ebl * GLD + 1 * HS + ejj] + bi_f;
            float gg2 = Gsm[ebl * GLD + 2 * HS + ejj] + bi_g;
            float go  = Gsm[ebl * GLD + 3 * HS + ejj] + bi_o;
            float iv = sigf(gi), fv = sigf(gf), gv = tanh_f(gg2), ov = sigf(go);
            creg = fv * creg + iv * gv;
            float h = ov * tanh_f(creg);
            unsigned hb16 = (unsigned)f2b(h);

            // own-slice h for step s+1 goes through LDS (safe: MFMA2(s) reads of
            // Hb completed before bar C; bar D orders this write for s+1)
            Hb[ebl * LDK + j0 + ejj] = (unsigned short)hb16;

            // tagged packet for the other 4 slices (fire-and-forget, agent scope)
            __hip_atomic_store(hxd + ((s + 1) & 1) * HXSLOT + (b0 + ebl) * HXW + (j0 + ejj),
                               (hb16 << 16) | (unsigned)s,
                               __ATOMIC_RELAXED, __HIP_MEMORY_SCOPE_AGENT);

            float hn = __shfl_down(h, 1);          // partner (ejj+1) in same wave
            if (pub) {
                unsigned pkt = hb16 | ((unsigned)f2b(hn) << 16);
                __hip_atomic_store((unsigned int*)g_hcat
                                       + (((size_t)((b0 + ebl) * Tn + t)) * (2 * Hn) + dir * Hn + j0 + ejj) / 2,
                                   pkt, __ATOMIC_RELAXED, __HIP_MEMORY_SCOPE_AGENT);
            }
        }

        // writeback prefetched emb(s+1) -> Aemb[nxt] (covered by bar D)
        if (do_pf) {
#pragma unroll
            for (int k = 0; k < 2; k++) {
                int i = tid + k * NTHR;
                if (i < MC * 80) {
                    int r = i / 80, c = i - r * 80;
                    s4v v = {0, 0, 0, 0};
                    if (c < 75) {
                        v[0] = (short)f2b(pf[k].x); v[1] = (short)f2b(pf[k].y);
                        v[2] = (short)f2b(pf[k].z); v[3] = (short)f2b(pf[k].w);
                    }
                    *(s4v*)&Aemb[nxt][r * LDK + c * 4] = v;
                }
            }
        }
        bar_lgkm();   // bar D: Aemb[nxt] + Hb self-write visible (LDS only)
    }
}

// ---------------- K2: fused out-projection + softmax, one wave per 16 positions ----------------
__global__ __launch_bounds__(256) void k_out(
    const float* __restrict__ W_lin, const float* __restrict__ b_lin, float* __restrict__ out)
{
    __shared__ float Wl[On * 2 * Hn];  // 21.6 KB
    __shared__ float bl[On];
    const int tid = threadIdx.x;
    for (int i = tid; i < On * 2 * Hn; i += 256) Wl[i] = W_lin[i];
    if (tid < On) bl[tid] = b_lin[tid];
    __syncthreads();

    const int lane = tid & 63;
    const int w    = tid >> 6;
    const int wg   = blockIdx.x * 4 + w;      // 4096 waves
    for (int it = 0; it < 16; it++) {
        const int p = wg * 16 + it;           // 0..65535
        const unsigned short* row = g_hcat + (size_t)p * (2 * Hn);
        float part[On];
#pragma unroll
        for (int o = 0; o < On; o++) part[o] = 0.f;
        for (int c = 0; c < 10; c++) {
            int k = lane + 64 * c;
            if (k < 2 * Hn) {
                float v = b2f(row[k]);
#pragma unroll
                for (int o = 0; o < On; o++) part[o] += v * Wl[o * (2 * Hn) + k];
            }
        }
#pragma unroll
        for (int off = 32; off >= 1; off >>= 1) {
#pragma unroll
            for (int o = 0; o < On; o++) part[o] += __shfl_xor(part[o], off, 64);
        }
        if (lane == 0) {
            float lg[On];
            float m = -1e30f;
#pragma unroll
            for (int o = 0; o < On; o++) { lg[o] = part[o] + bl[o]; m = fmaxf(m, lg[o]); }
            float ssum = 0.f;
#pragma unroll
            for (int o = 0; o < On; o++) { lg[o] = __expf(lg[o] - m); ssum += lg[o]; }
            float inv = 1.f / ssum;
#pragma unroll
            for (int o = 0; o < On; o++) out[(size_t)p * On + o] = lg[o] * inv;
        }
    }
}

// ---------------- host launcher ----------------
extern "C" void kernel_launch(void* const* d_in, const int* in_sizes, int n_in,
                              void* d_out, int out_size, void* d_ws, size_t ws_size,
                              hipStream_t stream)
{
    (void)in_sizes; (void)n_in; (void)out_size; (void)d_ws; (void)ws_size;
    const int* x = (const int*)d_in[0];
    const float* emb   = (const float*)d_in[1];
    const float* Wih_f = (const float*)d_in[2];
    const float* Whh_f = (const float*)d_in[3];
    const float* bf    = (const float*)d_in[4];
    const float* Wih_b = (const float*)d_in[5];
    const float* Whh_b = (const float*)d_in[6];
    const float* bb    = (const float*)d_in[7];
    const float* Wlin  = (const float*)d_in[8];
    const float* blin  = (const float*)d_in[9];
    float* out = (float*)d_out;

    k_zero<<<128, 256, 0, stream>>>();

    void* args[] = {
        (void*)&x, (void*)&emb,
        (void*)&Wih_f, (void*)&Whh_f, (void*)&bf,
        (void*)&Wih_b, (void*)&Whh_b, (void*)&bb
    };
    hipLaunchCooperativeKernel((const void*)k_lstm, dim3(NBLK), dim3(NTHR), args, 0, stream);

    k_out<<<1024, 256, 0, stream>>>(Wlin, blin, out);
}